// Round 9
// baseline (263.979 us; speedup 1.0000x reference)
//
#include <hip/hip_runtime.h>

#define MDIM 8192
#define NDIM 8192
#define KDIM 64

typedef __attribute__((ext_vector_type(8))) short bf16x8;
typedef __attribute__((ext_vector_type(4))) float f32x4;

__device__ __forceinline__ unsigned short f32_to_bf16(float f) {
    union { float f; unsigned int u; } v;
    v.f = f;
    unsigned int u = v.u;
    u += 0x7FFFu + ((u >> 16) & 1u);  // round-to-nearest-even
    return (unsigned short)(u >> 16);
}

// ---------------------------------------------------------------------------
// R9: occupancy experiment. 64x128 tile -> 24 KB LDS -> 6 blocks/CU
// (vs 3-4 in every prior round). Theory: barriers phase-lock all 4 waves of a
// block, so with only 3-4 resident blocks the CU's store-issue duty cycle is
// the global limiter (the 6.4 TB/s fill stores with 100% duty). More resident
// blocks -> more uncorrelated store phases per CU -> higher duty.
// All inner code is byte-identical proven R6/R7/R8 structure.
//
// LDS (ushort units, granule = 8 ushorts = 16 B), XOR-swizzled (R2 layout):
//   sA [64 m][64 k]:  elem (r,k) at r*64 + ((k>>3) ^ (r&7))*8 + (k&7)
//   sB [128 n][64 k]: same formula per n-row.
// Epilogue slabs (4 KB/wave, 16 KB total) recycle smem post-compute.
// ---------------------------------------------------------------------------
__global__ __launch_bounds__(256, 6)
void tmatmul_kernel(const float* __restrict__ A, const float* __restrict__ B,
                    float* __restrict__ C) {
    __shared__ __align__(16) unsigned short smem[12288];  // 24 KB
    unsigned short* sA = smem;         // 8 KB
    unsigned short* sB = smem + 4096;  // 16 KB

    const int tid = threadIdx.x;
    const int m0 = blockIdx.y << 6;  // 64-row band
    const int n0 = blockIdx.x << 7;  // 128-col band

    // ---- Stage A: 64x64 fp32 (contiguous 16 KB), linear float4 reads. ----
#pragma unroll
    for (int i = 0; i < 4; ++i) {
        const int f = (i << 10) + (tid << 2);  // linear float idx in tile
        const int row = f >> 6;
        const int col = f & 63;
        const float4 v = *reinterpret_cast<const float4*>(&A[(size_t)m0 * KDIM + f]);
        ushort4 h;
        h.x = f32_to_bf16(v.x);
        h.y = f32_to_bf16(v.y);
        h.z = f32_to_bf16(v.z);
        h.w = f32_to_bf16(v.w);
        *reinterpret_cast<ushort4*>(
            &sA[row * 64 + (((col >> 3) ^ (row & 7)) << 3) + (col & 7)]) = h;
    }

    // ---- Stage B: 64x128 fp32 transposed into sB[n][k] (R6 pattern). ----
#pragma unroll
    for (int i = 0; i < 8; ++i) {
        const int n = (tid & 63) + ((i & 1) << 6);           // 0..127
        const int k0 = ((tid >> 6) << 2) + ((i >> 1) << 4);  // 0,4,...,60
        const size_t gb = (size_t)k0 * NDIM + n0 + n;
        ushort4 h;
        h.x = f32_to_bf16(B[gb]);
        h.y = f32_to_bf16(B[gb + NDIM]);
        h.z = f32_to_bf16(B[gb + 2 * NDIM]);
        h.w = f32_to_bf16(B[gb + 3 * NDIM]);
        *reinterpret_cast<ushort4*>(
            &sB[n * 64 + (((k0 >> 3) ^ (n & 7)) << 3) + (k0 & 7)]) = h;
    }

    __syncthreads();

    // ---- Compute: 4 waves in 2x2 over 64x128; wave strip = 32 x 64
    //      (2 mt x 4 nt MFMA tiles, K=64 = 2 steps). ----
    const int lane = tid & 63;
    const int wv = tid >> 6;
    const int wm = (wv >> 1) << 5;  // 0 or 32
    const int wn = (wv & 1) << 6;   // 0 or 64
    const int l15 = lane & 15;
    const int quad = lane >> 4;
    const int x = l15 & 7;  // row-dependent XOR key
    const char* sAb = (const char*)sA;
    const char* sBb = (const char*)sB;

    bf16x8 afrag[2][2];
#pragma unroll
    for (int mt = 0; mt < 2; ++mt)
#pragma unroll
        for (int ks = 0; ks < 2; ++ks)
            afrag[mt][ks] = *reinterpret_cast<const bf16x8*>(
                sAb + (wm + mt * 16 + l15) * 128 + (((ks * 4 + quad) ^ x) << 4));

    f32x4 acc[2][4];
    const f32x4 zero = {0.0f, 0.0f, 0.0f, 0.0f};
#pragma unroll
    for (int mt = 0; mt < 2; ++mt)
#pragma unroll
        for (int nt = 0; nt < 4; ++nt)
            acc[mt][nt] = zero;

    // Operand swap (proven): lane holds C[m = wm+mt*16+l15][n = wn+nt*16+quad*4+reg].
#pragma unroll
    for (int nt = 0; nt < 4; ++nt) {
        const char* rb = sBb + (wn + nt * 16 + l15) * 128;
        const bf16x8 bf0 = *reinterpret_cast<const bf16x8*>(rb + ((quad ^ x) << 4));
        const bf16x8 bf1 =
            *reinterpret_cast<const bf16x8*>(rb + (((4 + quad) ^ x) << 4));
#pragma unroll
        for (int mt = 0; mt < 2; ++mt) {
            acc[mt][nt] = __builtin_amdgcn_mfma_f32_16x16x32_bf16(
                bf0, afrag[mt][0], acc[mt][nt], 0, 0, 0);
            acc[mt][nt] = __builtin_amdgcn_mfma_f32_16x16x32_bf16(
                bf1, afrag[mt][1], acc[mt][nt], 0, 0, 0);
        }
    }

    // All waves done reading sA/sB before LDS is recycled as bounce slabs.
    __syncthreads();

    // ---- Epilogue (R6 bounce, R8 single-slab): per 16x64 mt-slice, scatter
    //      into the wave's 4 KB slab (g at row r stored at g^r), re-read
    //      row-major, store 4 rows x 256 B per plain global_store_dwordx4. ----
    float* buf = reinterpret_cast<float*>((char*)smem + (wv << 12));
#pragma unroll
    for (int mt = 0; mt < 2; ++mt) {
#pragma unroll
        for (int nt = 0; nt < 4; ++nt) {
            const int g = (nt << 2) + quad;
            *reinterpret_cast<f32x4*>(&buf[(l15 << 6) + ((g ^ l15) << 2)]) =
                acc[mt][nt];
        }
        const int m_base = m0 + wm + (mt << 4);
        const int n_base = n0 + wn + (l15 << 2);
#pragma unroll
        for (int j = 0; j < 4; ++j) {
            const int rr = (j << 2) + quad;
            const f32x4 v = *reinterpret_cast<const f32x4*>(
                &buf[(rr << 6) + ((l15 ^ rr) << 2)]);
            *reinterpret_cast<f32x4*>(&C[(size_t)(m_base + rr) * NDIM + n_base]) = v;
        }
    }
}

extern "C" void kernel_launch(void* const* d_in, const int* in_sizes, int n_in,
                              void* d_out, int out_size, void* d_ws, size_t ws_size,
                              hipStream_t stream) {
    const float* A = (const float*)d_in[0];
    const float* B = (const float*)d_in[1];
    float* C = (float*)d_out;
    dim3 grid(NDIM / 128, MDIM / 64);  // (64, 128) = 8192 blocks
    tmatmul_kernel<<<grid, dim3(256, 1, 1), 0, stream>>>(A, B, C);
}